// Round 8
// baseline (887.061 us; speedup 1.0000x reference)
//
#include <hip/hip_runtime.h>
#include <hip/hip_bf16.h>
#include <math.h>

#define NE_N 50000
#define NM_N 50000
#define NEDGE 500000
#define NB1 392            // coarse buckets = ceil(100000/256)
#define NB1R (NB1 * 4)     // 4x replicated counters

typedef __attribute__((ext_vector_type(8))) short bf16x8;
typedef __attribute__((ext_vector_type(4))) float f32x4;

__device__ __forceinline__ ushort f2bf(float f) {
  uint u = __float_as_uint(f);
  u += 0x7fffu + ((u >> 16) & 1u);   // RNE
  return (ushort)(u >> 16);
}
__device__ __forceinline__ float bfl(uint u) { return __uint_as_float(u << 16); }
__device__ __forceinline__ float bfh(uint u) { return __uint_as_float(u & 0xffff0000u); }

// ---- composite weights: Wt[b] = bf16T(Win @ Wsrc), bc[b] = bin @ Wsrc ----
__global__ __launch_bounds__(256) void cmm_k(const float* WinE, const float* binE,
    const float* WsE, const float* WinM, const float* binM, const float* WsM,
    ushort* __restrict__ Wt, float* __restrict__ bc) {
  __shared__ float sB[128][128];
  const int b = blockIdx.x;
  const float* A   = b ? WinM : WinE;
  const float* bin = b ? binM : binE;
  const float* B   = b ? WsM  : WsE;
  const int tid = threadIdx.x;
  for (int i = tid; i < 16384; i += 256) sB[i >> 7][i & 127] = B[i];
  __syncthreads();
  const int r = tid >> 1, c0 = (tid & 1) * 64;
  float acc[64];
#pragma unroll
  for (int j = 0; j < 64; ++j) acc[j] = 0.f;
  for (int k = 0; k < 128; ++k) {
    float a = A[r * 128 + k];
#pragma unroll
    for (int j = 0; j < 64; ++j) acc[j] = fmaf(a, sB[k][c0 + j], acc[j]);
  }
  ushort* o = Wt + (size_t)b * 16384;
  for (int j = 0; j < 64; ++j) o[(c0 + j) * 128 + r] = f2bf(acc[j]);
  if (tid < 128) {
    float s = 0.f;
    for (int k = 0; k < 128; ++k) s = fmaf(bin[k], sB[k][tid], s);
    bc[b * 128 + tid] = s;
  }
}

// ---- cast + transpose 3 plain GEMM weights into Wt[2..4] ------------------
__global__ __launch_bounds__(256) void wcast3_k(const float* W0, const float* W1,
                                                const float* W2, ushort* __restrict__ Wt) {
  __shared__ float T[128][129];
  const float* W = (blockIdx.x == 0) ? W0 : (blockIdx.x == 1) ? W1 : W2;
  int tid = threadIdx.x;
  for (int i = tid; i < 16384; i += 256) T[i >> 7][i & 127] = W[i];
  __syncthreads();
  uint* o = (uint*)(Wt + (size_t)(2 + blockIdx.x) * 16384);
  for (int i = tid; i < 8192; i += 256) {
    int n = i >> 6, k2 = (i & 63) << 1;
    o[i] = (uint)f2bf(T[k2][n]) | ((uint)f2bf(T[k2 + 1][n]) << 16);
  }
}

// ---- V[k,h] folds for the 4 dst attention vectors -------------------------
__global__ void vfold4_k(const float* __restrict__ Wem, const float* __restrict__ aem,
                         const float* __restrict__ Wme, const float* __restrict__ ame,
                         float* __restrict__ Vbase) {
  int idx = blockIdx.x;   // 0=em0 1=me0 2=em1 3=me1
  int layer = idx >> 1, et = idx & 1;
  const float* W = (et ? Wme : Wem) + layer * 16384;
  const float* a = (et ? ame : aem) + layer * 128;
  float* V = Vbase + idx * 512;
  int t = threadIdx.x;  // 512
  int k = t >> 2, h = t & 3;
  float s = 0.f;
#pragma unroll
  for (int d = 0; d < 32; ++d) s += W[k * 128 + h * 32 + d] * a[h * 32 + d];
  V[k * 4 + h] = s;
}

// ---- composite dst-logit maps: VcT = bf16((Win @ v0)^T), bias4 = bin @ v0 -
__global__ __launch_bounds__(512) void smallprep_k(const float* WinE, const float* binE,
    const float* WinM, const float* binM, const float* __restrict__ Vb,
    ushort* __restrict__ VcTa, ushort* __restrict__ VcTb, float* __restrict__ bias4) {
  const int b = blockIdx.x;
  const float* Win = b ? WinM : WinE;
  const float* bin = b ? binM : binE;
  const float* v0  = b ? Vb : Vb + 512;
  ushort* VcT = b ? VcTb : VcTa;
  int t = threadIdx.x;
  int c = t & 3, k = t >> 2;
  float s = 0.f;
  for (int j = 0; j < 128; ++j) s = fmaf(Win[k * 128 + j], v0[j * 4 + c], s);
  VcT[c * 128 + k] = f2bf(s);
  for (int z = t; z < 12 * 128; z += 512) VcT[512 + z] = 0;  // pad rows 4..15
  if (t < 4) {
    float s2 = 0.f;
    for (int j = 0; j < 128; ++j) s2 = fmaf(bin[j], v0[j * 4 + t], s2);
    bias4[b * 4 + t] = s2;
  }
}

// ---- MFMA bf16 GEMM (same as R6) ------------------------------------------
__global__ __launch_bounds__(256) void mgemm_k(const ushort* __restrict__ A,
    const float* __restrict__ Af,
    const ushort* __restrict__ Wt, const float* __restrict__ bias,
    ushort* __restrict__ Cb, int M, int act,
    const float* __restrict__ aV, float* __restrict__ alsOut,
    const ushort* __restrict__ VcT, const float* __restrict__ bias4,
    float* __restrict__ ald4Out) {
  __shared__ char smem[69632];
  char* sA = smem;
  char* sW = smem + 32768;
  char* sV = smem + 65536;
  const int tid = threadIdx.x;
  const int row0 = blockIdx.x * 128;
#pragma unroll
  for (int i = 0; i < 8; ++i) {
    int l = (tid + i * 256) << 4;
    int rl = l >> 8;
    int rg = row0 + rl; rg = rg < M ? rg : M - 1;
    if (Af) {
      int c0f = (l & 255) >> 1;
      float4 a = *(const float4*)&Af[(size_t)rg * 128 + c0f];
      float4 b = *(const float4*)&Af[(size_t)rg * 128 + c0f + 4];
      ushort r[8] = {f2bf(a.x), f2bf(a.y), f2bf(a.z), f2bf(a.w),
                     f2bf(b.x), f2bf(b.y), f2bf(b.z), f2bf(b.w)};
      *(uint4*)(sA + (l ^ ((rl & 7) << 4))) = *(uint4*)r;
    } else {
      uint4 v = *(const uint4*)((const char*)A + (size_t)rg * 256 + (l & 255));
      *(uint4*)(sA + (l ^ ((rl & 7) << 4))) = v;
    }
    uint4 w = *(const uint4*)((const char*)Wt + l);
    *(uint4*)(sW + (l ^ ((rl & 7) << 4))) = w;
  }
  if (VcT) {
    int l = tid << 4;
    int rl = l >> 8;
    uint4 v = *(const uint4*)((const char*)VcT + l);
    *(uint4*)(sV + (l ^ ((rl & 7) << 4))) = v;
  }
  __syncthreads();
  const int lane = tid & 63, wid = tid >> 6;
  const int l15 = lane & 15, lq = lane >> 4;
  const int wm = wid * 32;
  f32x4 acc[2][8];
  f32x4 accd[2];
  {
    f32x4 z = {0.f, 0.f, 0.f, 0.f};
#pragma unroll
    for (int mt = 0; mt < 2; ++mt) {
      accd[mt] = z;
#pragma unroll
      for (int nt = 0; nt < 8; ++nt) acc[mt][nt] = z;
    }
  }
#pragma unroll
  for (int ks = 0; ks < 4; ++ks) {
    int r0r = wm + l15;
    int o0 = (r0r << 8) + (ks << 6) + (lq << 4);
    bf16x8 af0 = *(const bf16x8*)(sA + (o0 ^ ((r0r & 7) << 4)));
    int r1r = r0r + 16;
    int o1 = (r1r << 8) + (ks << 6) + (lq << 4);
    bf16x8 af1 = *(const bf16x8*)(sA + (o1 ^ ((r1r & 7) << 4)));
    if (VcT) {
      int ov = (l15 << 8) + (ks << 6) + (lq << 4);
      bf16x8 vf = *(const bf16x8*)(sV + (ov ^ ((l15 & 7) << 4)));
      accd[0] = __builtin_amdgcn_mfma_f32_16x16x32_bf16(af0, vf, accd[0], 0, 0, 0);
      accd[1] = __builtin_amdgcn_mfma_f32_16x16x32_bf16(af1, vf, accd[1], 0, 0, 0);
    }
#pragma unroll
    for (int nt = 0; nt < 8; ++nt) {
      int c = (nt << 4) + l15;
      int ob = (c << 8) + (ks << 6) + (lq << 4);
      bf16x8 bf = *(const bf16x8*)(sW + (ob ^ ((c & 7) << 4)));
      acc[0][nt] = __builtin_amdgcn_mfma_f32_16x16x32_bf16(af0, bf, acc[0][nt], 0, 0, 0);
      acc[1][nt] = __builtin_amdgcn_mfma_f32_16x16x32_bf16(af1, bf, acc[1][nt], 0, 0, 0);
    }
  }
  float aVv[8], bv[8];
#pragma unroll
  for (int nt = 0; nt < 8; ++nt) {
    int c = (nt << 4) + l15;
    aVv[nt] = aV ? aV[c] : 0.f;
    bv[nt] = bias ? bias[c] : 0.f;
  }
#pragma unroll
  for (int mt = 0; mt < 2; ++mt)
#pragma unroll
    for (int nt = 0; nt < 8; ++nt)
#pragma unroll
      for (int rg = 0; rg < 4; ++rg) {
        float v = acc[mt][nt][rg] + bv[nt];
        if (act) v = fmaxf(v, 0.f);
        acc[mt][nt][rg] = v;
      }
  if (aV) {
#pragma unroll
    for (int mt = 0; mt < 2; ++mt)
#pragma unroll
      for (int rg = 0; rg < 4; ++rg) {
        float p0 = fmaf(acc[mt][0][rg], aVv[0], acc[mt][1][rg] * aVv[1]);
        float p1 = fmaf(acc[mt][2][rg], aVv[2], acc[mt][3][rg] * aVv[3]);
        float p2 = fmaf(acc[mt][4][rg], aVv[4], acc[mt][5][rg] * aVv[5]);
        float p3 = fmaf(acc[mt][6][rg], aVv[6], acc[mt][7][rg] * aVv[7]);
#pragma unroll
        for (int off = 1; off < 16; off <<= 1) {
          p0 += __shfl_xor(p0, off, 64);
          p1 += __shfl_xor(p1, off, 64);
          p2 += __shfl_xor(p2, off, 64);
          p3 += __shfl_xor(p3, off, 64);
        }
        int r = row0 + wm + mt * 16 + lq * 4 + rg;
        if (l15 == 0 && r < M)
          *(float4*)&alsOut[(size_t)r * 4] = make_float4(p0, p1, p2, p3);
      }
  }
  if (VcT) {
    float b4 = (l15 < 4) ? bias4[l15] : 0.f;
#pragma unroll
    for (int mt = 0; mt < 2; ++mt)
#pragma unroll
      for (int rg = 0; rg < 4; ++rg) {
        int r = row0 + wm + mt * 16 + lq * 4 + rg;
        if (l15 < 4 && r < M) ald4Out[(size_t)r * 4 + l15] = accd[mt][rg] + b4;
      }
  }
  __syncthreads();
#pragma unroll
  for (int mt = 0; mt < 2; ++mt)
#pragma unroll
    for (int nt = 0; nt < 8; ++nt)
#pragma unroll
      for (int rg = 0; rg < 4; ++rg) {
        int r = wm + mt * 16 + lq * 4 + rg;
        int c = (nt << 4) + l15;
        *(ushort*)(sA + ((r << 8) + ((c << 1) ^ ((r & 7) << 4)))) =
            f2bf(acc[mt][nt][rg]);
      }
  __syncthreads();
#pragma unroll
  for (int i = 0; i < 8; ++i) {
    int l = (tid + i * 256) << 4;
    int rl = l >> 8;
    if (row0 + rl < M)
      *(uint4*)((char*)Cb + (size_t)row0 * 256 + l) =
          *(const uint4*)(sA + (l ^ ((rl & 7) << 4)));
  }
}

// ---- histogram: fine (100k) + coarse replicated (392x4) -------------------
__global__ void histB_k(const int* __restrict__ de, const int* __restrict__ dm,
                        int* __restrict__ cnt, int* __restrict__ cnt1r) {
  int e = blockIdx.x * 256 + threadIdx.x;
  if (e >= 2 * NEDGE) return;
  int db = (e < NEDGE) ? de[e] : NM_N + dm[e - NEDGE];
  atomicAdd(&cnt[db], 1);
  atomicAdd(&cnt1r[((db >> 8) << 2) + (blockIdx.x & 3)], 1);
}

__global__ __launch_bounds__(256) void scanA_k(const int* __restrict__ cnt,
                                               int* __restrict__ offs,
                                               int* __restrict__ sums, int n) {
  __shared__ int ts[256];
  int tid = threadIdx.x;
  int base = blockIdx.x * 4096 + tid * 16;
  int v[16];
  int s = 0;
#pragma unroll
  for (int i = 0; i < 16; ++i) {
    v[i] = (base + i < n) ? cnt[base + i] : 0;
    s += v[i];
  }
  ts[tid] = s;
  __syncthreads();
  for (int off = 1; off < 256; off <<= 1) {
    int t = (tid >= off) ? ts[tid - off] : 0;
    __syncthreads();
    ts[tid] += t;
    __syncthreads();
  }
  int run = ts[tid] - s;
#pragma unroll
  for (int i = 0; i < 16; ++i) {
    if (base + i < n) offs[base + i] = run;
    run += v[i];
  }
  if (tid == 255) sums[blockIdx.x] = ts[255];
}

__global__ void scanB_k(int* __restrict__ sums, int nchunk) {
  if (threadIdx.x == 0) {
    int acc = 0;
    for (int i = 0; i < nchunk; ++i) {
      int t = sums[i];
      sums[i] = acc;
      acc += t;
    }
    sums[nchunk] = acc;
  }
}

__global__ void scanC_k(int* __restrict__ offs, const int* __restrict__ sums, int n) {
  int i = blockIdx.x * blockDim.x + threadIdx.x;
  if (i < n) offs[i] += sums[i >> 12];
  if (i == 0) offs[n] = sums[(n + 4095) >> 12];
}

// ---- two-level scatter ----------------------------------------------------
__global__ void scatterA_k(const int* __restrict__ se, const int* __restrict__ de,
                           const int* __restrict__ sm, const int* __restrict__ dm,
                           const int* __restrict__ offs1r, int* __restrict__ cur1r,
                           uint2* __restrict__ tmp) {
  int e = blockIdx.x * 256 + threadIdx.x;
  if (e >= 2 * NEDGE) return;
  int s, db;
  if (e < NEDGE) { s = se[e]; db = de[e]; }
  else { s = sm[e - NEDGE]; db = NM_N + dm[e - NEDGE]; }
  int b = ((db >> 8) << 2) + (blockIdx.x & 3);
  int pos = offs1r[b] + atomicAdd(&cur1r[b], 1);
  tmp[pos] = make_uint2((uint)s, (uint)db);
}

__global__ void scatterB_k(const uint2* __restrict__ tmp, const int* __restrict__ offs,
                           int* __restrict__ cur, int* __restrict__ ssrc) {
  int e = blockIdx.x * 256 + threadIdx.x;
  if (e >= 2 * NEDGE) return;
  uint2 t = tmp[e];
  int pos = offs[t.y] + atomicAdd(&cur[t.y], 1);
  ssrc[pos] = (int)t.x;
}

// ---- per-dst softmax aggregation (bf16 hs), unshifted exp, 8-wide ---------
__global__ __launch_bounds__(256) void gat_agg_k(const ushort* __restrict__ hs,
    const float* __restrict__ als, const float* __restrict__ ald,
    const int* __restrict__ offs, const int* __restrict__ ssrc,
    const float* __restrict__ bias, float* __restrict__ out,
    ushort* __restrict__ outB, int Ndst,
    const float* __restrict__ Vald, float* __restrict__ aldOut) {
  const int lane = threadIdx.x & 63;
  const int n = (blockIdx.x * 256 + threadIdx.x) >> 6;
  if (n >= Ndst) return;
  const int h = lane >> 4;
  const uint* hsu = (const uint*)hs;
  const float ad = ald[(size_t)n * 4 + h];
  const int i0 = offs[n], i1 = offs[n + 1];
  float den0 = 0.f, den1 = 0.f, acc0 = 0.f, acc1 = 0.f;
  int i = i0;
  for (; i + 8 <= i1; i += 8) {
    int s[8];
#pragma unroll
    for (int k = 0; k < 8; ++k) s[k] = ssrc[i + k];
    float p[8];
#pragma unroll
    for (int k = 0; k < 8; ++k) {
      float e = als[(size_t)s[k] * 4 + h] + ad;
      e = (e > 0.f) ? e : 0.2f * e;
      p[k] = __expf(e);
    }
    uint u[8];
#pragma unroll
    for (int k = 0; k < 8; ++k) u[k] = hsu[(size_t)s[k] * 64 + lane];
#pragma unroll
    for (int k = 0; k < 8; ++k) {
      acc0 = fmaf(p[k], bfl(u[k]), acc0);
      acc1 = fmaf(p[k], bfh(u[k]), acc1);
      if (k & 1) den1 += p[k]; else den0 += p[k];
    }
  }
  for (; i < i1; ++i) {
    int s0 = ssrc[i];
    float e = als[(size_t)s0 * 4 + h] + ad;
    e = (e > 0.f) ? e : 0.2f * e;
    float p0 = __expf(e);
    uint u0 = hsu[(size_t)s0 * 64 + lane];
    acc0 = fmaf(p0, bfl(u0), acc0);
    acc1 = fmaf(p0, bfh(u0), acc1);
    den0 += p0;
  }
  const float inv = 1.f / (den0 + den1 + 1e-16f);
  float r0 = acc0 * inv + bias[2 * lane];
  float r1 = acc1 * inv + bias[2 * lane + 1];
  r0 = (r0 > 0.f) ? r0 : expm1f(r0);  // ELU
  r1 = (r1 > 0.f) ? r1 : expm1f(r1);
  if (out)
    *(float2*)&out[(size_t)n * 128 + 2 * lane] = make_float2(r0, r1);
  if (outB)
    ((uint*)outB)[(size_t)n * 64 + lane] = (uint)f2bf(r0) | ((uint)f2bf(r1) << 16);
  if (Vald) {
    const float4 w0 = *(const float4*)&Vald[(2 * lane) * 4];
    const float4 w1 = *(const float4*)&Vald[(2 * lane + 1) * 4];
    float t0 = fmaf(r0, w0.x, r1 * w1.x);
    float t1 = fmaf(r0, w0.y, r1 * w1.y);
    float t2 = fmaf(r0, w0.z, r1 * w1.z);
    float t3 = fmaf(r0, w0.w, r1 * w1.w);
#pragma unroll
    for (int off = 1; off < 64; off <<= 1) {
      t0 += __shfl_xor(t0, off, 64);
      t1 += __shfl_xor(t1, off, 64);
      t2 += __shfl_xor(t2, off, 64);
      t3 += __shfl_xor(t3, off, 64);
    }
    if (lane == 0)
      *(float4*)&aldOut[(size_t)n * 4] = make_float4(t0, t1, t2, t3);
  }
}

// ---- fused regressor tail: pred = relu(h1(bf16)@W2+b2) @ W3 + b3 ----------
__global__ __launch_bounds__(256) void regfuse_k(const ushort* __restrict__ h1,
    const float* __restrict__ W2, const float* __restrict__ b2,
    const float* __restrict__ W3, const float* __restrict__ b3,
    float* __restrict__ pred, int M) {
  __shared__ float X[64][132];
  const int tid = threadIdx.x;
  const int row0 = blockIdx.x * 64;
#pragma unroll
  for (int i = 0; i < 4; ++i) {
    int q = tid + i * 256;
    int r = q >> 4, c8 = (q & 15) << 3;
    uint4 v = make_uint4(0, 0, 0, 0);
    if (row0 + r < M) v = *(const uint4*)&h1[(size_t)(row0 + r) * 128 + c8];
    X[r][c8 + 0] = bfl(v.x); X[r][c8 + 1] = bfh(v.x);
    X[r][c8 + 2] = bfl(v.y); X[r][c8 + 3] = bfh(v.y);
    X[r][c8 + 4] = bfl(v.z); X[r][c8 + 5] = bfh(v.z);
    X[r][c8 + 6] = bfl(v.w); X[r][c8 + 7] = bfh(v.w);
  }
  __syncthreads();
  const int cg = tid & 15, rq = tid >> 4;
  const int c0 = cg * 4;
  float acc[4][4];
#pragma unroll
  for (int s = 0; s < 4; ++s)
#pragma unroll
    for (int j = 0; j < 4; ++j) acc[s][j] = 0.f;
#pragma unroll 4
  for (int k = 0; k < 128; ++k) {
    float xv[4] = {X[rq][k], X[rq + 16][k], X[rq + 32][k], X[rq + 48][k]};
    float4 w = *(const float4*)&W2[k * 64 + c0];
#pragma unroll
    for (int s = 0; s < 4; ++s) {
      acc[s][0] = fmaf(xv[s], w.x, acc[s][0]);
      acc[s][1] = fmaf(xv[s], w.y, acc[s][1]);
      acc[s][2] = fmaf(xv[s], w.z, acc[s][2]);
      acc[s][3] = fmaf(xv[s], w.w, acc[s][3]);
    }
  }
  float4 bq = *(const float4*)&b2[c0];
  float4 w3 = *(const float4*)&W3[c0];
  float bb[4] = {bq.x, bq.y, bq.z, bq.w};
  float ww[4] = {w3.x, w3.y, w3.z, w3.w};
#pragma unroll
  for (int s = 0; s < 4; ++s) {
    float v = 0.f;
#pragma unroll
    for (int j = 0; j < 4; ++j) v = fmaf(fmaxf(acc[s][j] + bb[j], 0.f), ww[j], v);
    v += __shfl_xor(v, 1, 64);
    v += __shfl_xor(v, 2, 64);
    v += __shfl_xor(v, 4, 64);
    v += __shfl_xor(v, 8, 64);
    int r = row0 + rq + 16 * s;
    if (cg == 0 && r < M) pred[r] = v + b3[0];
  }
}

extern "C" void kernel_launch(void* const* d_in, const int* in_sizes, int n_in,
                              void* d_out, int out_size, void* d_ws, size_t ws_size,
                              hipStream_t stream) {
  const float* x_exp   = (const float*)d_in[0];
  const float* x_mat   = (const float*)d_in[1];
  const int*   ei_em   = (const int*)d_in[2];
  const int*   ei_me   = (const int*)d_in[3];
  const float* Win_exp = (const float*)d_in[4];
  const float* bin_exp = (const float*)d_in[5];
  const float* Win_mat = (const float*)d_in[6];
  const float* bin_mat = (const float*)d_in[7];
  const float* Wsrc_em = (const float*)d_in[8];
  const float* Wdst_em = (const float*)d_in[9];
  const float* asrc_em = (const float*)d_in[10];
  const float* adst_em = (const float*)d_in[11];
  const float* b_em    = (const float*)d_in[12];
  const float* Wsrc_me = (const float*)d_in[13];
  const float* Wdst_me = (const float*)d_in[14];
  const float* asrc_me = (const float*)d_in[15];
  const float* adst_me = (const float*)d_in[16];
  const float* b_me    = (const float*)d_in[17];
  const float* Wr1     = (const float*)d_in[18];
  const float* br1     = (const float*)d_in[19];
  const float* Wr2     = (const float*)d_in[20];
  const float* br2     = (const float*)d_in[21];
  const float* Wr3     = (const float*)d_in[22];
  const float* br3     = (const float*)d_in[23];

  float* pred = (float*)d_out;
  float* heO  = pred + NE_N;
  float* hmO  = heO + (size_t)NE_N * 128;

  ushort* bufA  = (ushort*)d_ws;                  // 4 x 12.8MB bf16 buffers
  ushort* bufB  = bufA + (size_t)6400000;
  ushort* bufC  = bufB + (size_t)6400000;
  ushort* bufD  = bufC + (size_t)6400000;
  uint2*  tmp   = (uint2*)(bufD + (size_t)6400000);  // 1M uint2 (8MB)
  ushort* Wt    = (ushort*)(tmp + 1000000);       // 5 x 16384 bf16
  ushort* VcTa  = Wt + 5 * 16384;                 // 16x128 bf16
  ushort* VcTb  = VcTa + 2048;
  float*  bc    = (float*)(VcTb + 2048);          // 2 x 128 composite biases
  float*  bias4 = bc + 256;                       // 2 x 4
  float*  alsE  = bias4 + 8;
  float*  alsM  = alsE + 200000;
  float*  aldE  = alsM + 200000;
  float*  aldM  = aldE + 200000;
  float*  Vb    = aldM + 200000;                  // 4 x 512 fp32 v0 folds
  int*    sums  = (int*)(Vb + 2048);              // 32
  int*    sums1 = sums + 32;                      // 4
  int*    cnt1r = sums1 + 4;                      // 1568 coarse replicated
  int*    offs1r= cnt1r + NB1R;                   // 1568
  int*    cur1r = offs1r + NB1R;                  // 1568
  int*    cnt   = cur1r + NB1R;                   // 100k (also reused as fine cur)
  int*    offs  = cnt + 100000;                   // 100001
  int*    ssrc  = offs + 100001;                  // 1M

  const int* se = ei_em;
  const int* de = ei_em + NEDGE;
  const int* sm = ei_me;
  const int* dm = ei_me + NEDGE;

  const int gE2 = (2 * NEDGE + 255) / 256;
  const int gWave = (NE_N + 3) / 4;
  const int gGemm = (NE_N + 127) / 128;
  const int nChunk = (100000 + 4095) / 4096;

  // ---- two-level counting sort (both edge types, 100k fine buckets) ----
  hipMemsetAsync(cnt, 0, 100000 * sizeof(int), stream);
  hipMemsetAsync(cnt1r, 0, NB1R * sizeof(int), stream);
  histB_k<<<gE2, 256, 0, stream>>>(de, dm, cnt, cnt1r);
  scanA_k<<<nChunk, 256, 0, stream>>>(cnt, offs, sums, 100000);
  scanB_k<<<1, 64, 0, stream>>>(sums, nChunk);
  scanC_k<<<(100000 + 255) / 256, 256, 0, stream>>>(offs, sums, 100000);
  scanA_k<<<1, 256, 0, stream>>>(cnt1r, offs1r, sums1, NB1R);  // single chunk
  hipMemsetAsync(cnt, 0, 100000 * sizeof(int), stream);
  hipMemsetAsync(cur1r, 0, NB1R * sizeof(int), stream);
  scatterA_k<<<gE2, 256, 0, stream>>>(se, de, sm, dm, offs1r, cur1r, tmp);
  scatterB_k<<<gE2, 256, 0, stream>>>(tmp, offs, cnt, ssrc);

  // ---- weight prep ----
  cmm_k<<<2, 256, 0, stream>>>(Win_exp, bin_exp, Wsrc_em, Win_mat, bin_mat,
                               Wsrc_me, Wt, bc);
  wcast3_k<<<3, 256, 0, stream>>>(Wsrc_em + 16384, Wsrc_me + 16384, Wr1, Wt);
  vfold4_k<<<4, 512, 0, stream>>>(Wdst_em, adst_em, Wdst_me, adst_me, Vb);
  smallprep_k<<<2, 512, 0, stream>>>(Win_exp, bin_exp, Win_mat, bin_mat, Vb,
                                     VcTa, VcTb, bias4);

  const int* offs_em = offs;
  const int* offs_me = offs + NM_N;

  // ---- layer 1 composite GEMMs: x -> hs (+als, +composite ald4) ----
  mgemm_k<<<gGemm, 256, 0, stream>>>(nullptr, x_exp, Wt, bc, bufC, NE_N, 0,
                                     asrc_em, alsE, VcTa, bias4, aldE);
  mgemm_k<<<gGemm, 256, 0, stream>>>(nullptr, x_mat, Wt + 16384, bc + 128, bufD,
                                     NM_N, 0, asrc_me, alsM, VcTb, bias4 + 4, aldM);

  // ---- layer 1 aggregations ----
  gat_agg_k<<<gWave, 256, 0, stream>>>(bufC, alsE, aldM, offs_em, ssrc, b_em,
                                       nullptr, bufA, NM_N, Vb + 1024, aldM);  // hm1
  gat_agg_k<<<gWave, 256, 0, stream>>>(bufD, alsM, aldE, offs_me, ssrc, b_me,
                                       nullptr, bufB, NE_N, Vb + 1536, aldE);  // he1

  // ---- layer 2 GEMMs ----
  mgemm_k<<<gGemm, 256, 0, stream>>>(bufB, nullptr, Wt + 2 * 16384, nullptr, bufC,
                                     NE_N, 0, asrc_em + 128, alsE,
                                     nullptr, nullptr, nullptr);
  mgemm_k<<<gGemm, 256, 0, stream>>>(bufA, nullptr, Wt + 3 * 16384, nullptr, bufD,
                                     NM_N, 0, asrc_me + 128, alsM,
                                     nullptr, nullptr, nullptr);

  // ---- layer 2 aggregations ----
  gat_agg_k<<<gWave, 256, 0, stream>>>(bufC, alsE, aldM, offs_em, ssrc,
                                       b_em + 128, hmO, nullptr, NM_N,
                                       nullptr, nullptr);
  gat_agg_k<<<gWave, 256, 0, stream>>>(bufD, alsM, aldE, offs_me, ssrc,
                                       b_me + 128, heO, bufA, NE_N,
                                       nullptr, nullptr);

  // ---- regressor ----
  mgemm_k<<<gGemm, 256, 0, stream>>>(bufA, nullptr, Wt + 4 * 16384, br1, bufB,
                                     NE_N, 1, nullptr, nullptr,
                                     nullptr, nullptr, nullptr);
  regfuse_k<<<(NE_N + 63) / 64, 256, 0, stream>>>(bufB, Wr2, br2, Wr3, br3,
                                                  pred, NE_N);
}

// Round 9
// 388.799 us; speedup vs baseline: 2.2815x; 2.2815x over previous
//
#include <hip/hip_runtime.h>
#include <hip/hip_bf16.h>
#include <math.h>

#define NE_N 50000
#define NM_N 50000
#define NEDGE 500000

typedef __attribute__((ext_vector_type(8))) short bf16x8;
typedef __attribute__((ext_vector_type(4))) float f32x4;

__device__ __forceinline__ ushort f2bf(float f) {
  uint u = __float_as_uint(f);
  u += 0x7fffu + ((u >> 16) & 1u);   // RNE
  return (ushort)(u >> 16);
}
__device__ __forceinline__ float bfl(uint u) { return __uint_as_float(u << 16); }
__device__ __forceinline__ float bfh(uint u) { return __uint_as_float(u & 0xffff0000u); }

// ---- composite weights: Wt[b] = bf16T(Win @ Wsrc), bc[b] = bin @ Wsrc ----
__global__ __launch_bounds__(256) void cmm_k(const float* WinE, const float* binE,
    const float* WsE, const float* WinM, const float* binM, const float* WsM,
    ushort* __restrict__ Wt, float* __restrict__ bc) {
  __shared__ float sB[128][128];
  const int b = blockIdx.x;
  const float* A   = b ? WinM : WinE;
  const float* bin = b ? binM : binE;
  const float* B   = b ? WsM  : WsE;
  const int tid = threadIdx.x;
  for (int i = tid; i < 16384; i += 256) sB[i >> 7][i & 127] = B[i];
  __syncthreads();
  const int r = tid >> 1, c0 = (tid & 1) * 64;
  float acc[64];
#pragma unroll
  for (int j = 0; j < 64; ++j) acc[j] = 0.f;
  for (int k = 0; k < 128; ++k) {
    float a = A[r * 128 + k];
#pragma unroll
    for (int j = 0; j < 64; ++j) acc[j] = fmaf(a, sB[k][c0 + j], acc[j]);
  }
  ushort* o = Wt + (size_t)b * 16384;
  for (int j = 0; j < 64; ++j) o[(c0 + j) * 128 + r] = f2bf(acc[j]);
  if (tid < 128) {
    float s = 0.f;
    for (int k = 0; k < 128; ++k) s = fmaf(bin[k], sB[k][tid], s);
    bc[b * 128 + tid] = s;
  }
}

// ---- cast + transpose 3 plain GEMM weights into Wt[2..4] ------------------
__global__ __launch_bounds__(256) void wcast3_k(const float* W0, const float* W1,
                                                const float* W2, ushort* __restrict__ Wt) {
  __shared__ float T[128][129];
  const float* W = (blockIdx.x == 0) ? W0 : (blockIdx.x == 1) ? W1 : W2;
  int tid = threadIdx.x;
  for (int i = tid; i < 16384; i += 256) T[i >> 7][i & 127] = W[i];
  __syncthreads();
  uint* o = (uint*)(Wt + (size_t)(2 + blockIdx.x) * 16384);
  for (int i = tid; i < 8192; i += 256) {
    int n = i >> 6, k2 = (i & 63) << 1;
    o[i] = (uint)f2bf(T[k2][n]) | ((uint)f2bf(T[k2 + 1][n]) << 16);
  }
}

// ---- V[k,h] folds for the 4 dst attention vectors -------------------------
__global__ void vfold4_k(const float* __restrict__ Wem, const float* __restrict__ aem,
                         const float* __restrict__ Wme, const float* __restrict__ ame,
                         float* __restrict__ Vbase) {
  int idx = blockIdx.x;   // 0=em0 1=me0 2=em1 3=me1
  int layer = idx >> 1, et = idx & 1;
  const float* W = (et ? Wme : Wem) + layer * 16384;
  const float* a = (et ? ame : aem) + layer * 128;
  float* V = Vbase + idx * 512;
  int t = threadIdx.x;  // 512
  int k = t >> 2, h = t & 3;
  float s = 0.f;
#pragma unroll
  for (int d = 0; d < 32; ++d) s += W[k * 128 + h * 32 + d] * a[h * 32 + d];
  V[k * 4 + h] = s;
}

// ---- composite dst-logit maps: VcT = bf16((Win @ v0)^T), bias4 = bin @ v0 -
__global__ __launch_bounds__(512) void smallprep_k(const float* WinE, const float* binE,
    const float* WinM, const float* binM, const float* __restrict__ Vb,
    ushort* __restrict__ VcTa, ushort* __restrict__ VcTb, float* __restrict__ bias4) {
  const int b = blockIdx.x;
  const float* Win = b ? WinM : WinE;
  const float* bin = b ? binM : binE;
  const float* v0  = b ? Vb : Vb + 512;
  ushort* VcT = b ? VcTb : VcTa;
  int t = threadIdx.x;
  int c = t & 3, k = t >> 2;
  float s = 0.f;
  for (int j = 0; j < 128; ++j) s = fmaf(Win[k * 128 + j], v0[j * 4 + c], s);
  VcT[c * 128 + k] = f2bf(s);
  for (int z = t; z < 12 * 128; z += 512) VcT[512 + z] = 0;  // pad rows 4..15
  if (t < 4) {
    float s2 = 0.f;
    for (int j = 0; j < 128; ++j) s2 = fmaf(bin[j], v0[j * 4 + t], s2);
    bias4[b * 4 + t] = s2;
  }
}

// ---- MFMA bf16 GEMM + optional fused regressor tail -----------------------
//  normal: Cb = bf16(act(A@Wt^T + bias)); epilogues als (aV), composite ald4 (VcT)
//  reg mode (pred!=0): h1 = relu(A@Wt^T+bias) -> LDS; h2 = relu(h1@W2+b2);
//                      pred = h2@W3 + b3   (Cb may be null)
__global__ __launch_bounds__(256) void mgemm_k(const ushort* __restrict__ A,
    const float* __restrict__ Af,
    const ushort* __restrict__ Wt, const float* __restrict__ bias,
    ushort* __restrict__ Cb, int M, int act,
    const float* __restrict__ aV, float* __restrict__ alsOut,
    const ushort* __restrict__ VcT, const float* __restrict__ bias4,
    float* __restrict__ ald4Out,
    const float* __restrict__ W2, const float* __restrict__ b2,
    const float* __restrict__ W3, const float* __restrict__ b3,
    float* __restrict__ pred) {
  __shared__ char smem[69632];
  char* sA = smem;
  char* sW = smem + 32768;
  char* sV = smem + 65536;
  const int tid = threadIdx.x;
  const int row0 = blockIdx.x * 128;
#pragma unroll
  for (int i = 0; i < 8; ++i) {
    int l = (tid + i * 256) << 4;
    int rl = l >> 8;
    int rg = row0 + rl; rg = rg < M ? rg : M - 1;
    if (Af) {
      int c0f = (l & 255) >> 1;
      float4 a = *(const float4*)&Af[(size_t)rg * 128 + c0f];
      float4 b = *(const float4*)&Af[(size_t)rg * 128 + c0f + 4];
      ushort r[8] = {f2bf(a.x), f2bf(a.y), f2bf(a.z), f2bf(a.w),
                     f2bf(b.x), f2bf(b.y), f2bf(b.z), f2bf(b.w)};
      *(uint4*)(sA + (l ^ ((rl & 7) << 4))) = *(uint4*)r;
    } else {
      uint4 v = *(const uint4*)((const char*)A + (size_t)rg * 256 + (l & 255));
      *(uint4*)(sA + (l ^ ((rl & 7) << 4))) = v;
    }
    uint4 w = *(const uint4*)((const char*)Wt + l);
    *(uint4*)(sW + (l ^ ((rl & 7) << 4))) = w;
  }
  if (VcT) {
    int l = tid << 4;
    int rl = l >> 8;
    uint4 v = *(const uint4*)((const char*)VcT + l);
    *(uint4*)(sV + (l ^ ((rl & 7) << 4))) = v;
  }
  __syncthreads();
  const int lane = tid & 63, wid = tid >> 6;
  const int l15 = lane & 15, lq = lane >> 4;
  const int wm = wid * 32;
  f32x4 acc[2][8];
  f32x4 accd[2];
  {
    f32x4 z = {0.f, 0.f, 0.f, 0.f};
#pragma unroll
    for (int mt = 0; mt < 2; ++mt) {
      accd[mt] = z;
#pragma unroll
      for (int nt = 0; nt < 8; ++nt) acc[mt][nt] = z;
    }
  }
#pragma unroll
  for (int ks = 0; ks < 4; ++ks) {
    int r0r = wm + l15;
    int o0 = (r0r << 8) + (ks << 6) + (lq << 4);
    bf16x8 af0 = *(const bf16x8*)(sA + (o0 ^ ((r0r & 7) << 4)));
    int r1r = r0r + 16;
    int o1 = (r1r << 8) + (ks << 6) + (lq << 4);
    bf16x8 af1 = *(const bf16x8*)(sA + (o1 ^ ((r1r & 7) << 4)));
    if (VcT) {
      int ov = (l15 << 8) + (ks << 6) + (lq << 4);
      bf16x8 vf = *(const bf16x8*)(sV + (ov ^ ((l15 & 7) << 4)));
      accd[0] = __builtin_amdgcn_mfma_f32_16x16x32_bf16(af0, vf, accd[0], 0, 0, 0);
      accd[1] = __builtin_amdgcn_mfma_f32_16x16x32_bf16(af1, vf, accd[1], 0, 0, 0);
    }
#pragma unroll
    for (int nt = 0; nt < 8; ++nt) {
      int c = (nt << 4) + l15;
      int ob = (c << 8) + (ks << 6) + (lq << 4);
      bf16x8 bf = *(const bf16x8*)(sW + (ob ^ ((c & 7) << 4)));
      acc[0][nt] = __builtin_amdgcn_mfma_f32_16x16x32_bf16(af0, bf, acc[0][nt], 0, 0, 0);
      acc[1][nt] = __builtin_amdgcn_mfma_f32_16x16x32_bf16(af1, bf, acc[1][nt], 0, 0, 0);
    }
  }
  float aVv[8], bv[8];
#pragma unroll
  for (int nt = 0; nt < 8; ++nt) {
    int c = (nt << 4) + l15;
    aVv[nt] = aV ? aV[c] : 0.f;
    bv[nt] = bias ? bias[c] : 0.f;
  }
#pragma unroll
  for (int mt = 0; mt < 2; ++mt)
#pragma unroll
    for (int nt = 0; nt < 8; ++nt)
#pragma unroll
      for (int rg = 0; rg < 4; ++rg) {
        float v = acc[mt][nt][rg] + bv[nt];
        if (act) v = fmaxf(v, 0.f);
        acc[mt][nt][rg] = v;
      }
  if (aV) {
#pragma unroll
    for (int mt = 0; mt < 2; ++mt)
#pragma unroll
      for (int rg = 0; rg < 4; ++rg) {
        float p0 = fmaf(acc[mt][0][rg], aVv[0], acc[mt][1][rg] * aVv[1]);
        float p1 = fmaf(acc[mt][2][rg], aVv[2], acc[mt][3][rg] * aVv[3]);
        float p2 = fmaf(acc[mt][4][rg], aVv[4], acc[mt][5][rg] * aVv[5]);
        float p3 = fmaf(acc[mt][6][rg], aVv[6], acc[mt][7][rg] * aVv[7]);
#pragma unroll
        for (int off = 1; off < 16; off <<= 1) {
          p0 += __shfl_xor(p0, off, 64);
          p1 += __shfl_xor(p1, off, 64);
          p2 += __shfl_xor(p2, off, 64);
          p3 += __shfl_xor(p3, off, 64);
        }
        int r = row0 + wm + mt * 16 + lq * 4 + rg;
        if (l15 == 0 && r < M)
          *(float4*)&alsOut[(size_t)r * 4] = make_float4(p0, p1, p2, p3);
      }
  }
  if (VcT) {
    float b4 = (l15 < 4) ? bias4[l15] : 0.f;
#pragma unroll
    for (int mt = 0; mt < 2; ++mt)
#pragma unroll
      for (int rg = 0; rg < 4; ++rg) {
        int r = row0 + wm + mt * 16 + lq * 4 + rg;
        if (l15 < 4 && r < M) ald4Out[(size_t)r * 4 + l15] = accd[mt][rg] + b4;
      }
  }
  // repack result bf16 into sA (swizzled); stage W2^T if reg mode
  __syncthreads();
#pragma unroll
  for (int mt = 0; mt < 2; ++mt)
#pragma unroll
    for (int nt = 0; nt < 8; ++nt)
#pragma unroll
      for (int rg = 0; rg < 4; ++rg) {
        int r = wm + mt * 16 + lq * 4 + rg;
        int c = (nt << 4) + l15;
        *(ushort*)(sA + ((r << 8) + ((c << 1) ^ ((r & 7) << 4)))) =
            f2bf(acc[mt][nt][rg]);
      }
  if (pred) {
    for (int i = tid; i < 8192; i += 256) {  // W2[128][64] -> sW[c][k] bf16
      int k = i >> 6, c = i & 63;
      *(ushort*)(sW + (((c << 8) + (k << 1)) ^ ((c & 7) << 4))) = f2bf(W2[i]);
    }
  }
  __syncthreads();
  if (Cb) {
#pragma unroll
    for (int i = 0; i < 8; ++i) {
      int l = (tid + i * 256) << 4;
      int rl = l >> 8;
      if (row0 + rl < M)
        *(uint4*)((char*)Cb + (size_t)row0 * 256 + l) =
            *(const uint4*)(sA + (l ^ ((rl & 7) << 4)));
    }
  }
  if (pred) {
    f32x4 a2[2][4];
    {
      f32x4 z = {0.f, 0.f, 0.f, 0.f};
#pragma unroll
      for (int mt = 0; mt < 2; ++mt)
#pragma unroll
        for (int nt = 0; nt < 4; ++nt) a2[mt][nt] = z;
    }
#pragma unroll
    for (int ks = 0; ks < 4; ++ks) {
      int r0r = wm + l15;
      int o0 = (r0r << 8) + (ks << 6) + (lq << 4);
      bf16x8 af0 = *(const bf16x8*)(sA + (o0 ^ ((r0r & 7) << 4)));
      int r1r = r0r + 16;
      int o1 = (r1r << 8) + (ks << 6) + (lq << 4);
      bf16x8 af1 = *(const bf16x8*)(sA + (o1 ^ ((r1r & 7) << 4)));
#pragma unroll
      for (int nt = 0; nt < 4; ++nt) {
        int c = (nt << 4) + l15;
        int ob = (c << 8) + (ks << 6) + (lq << 4);
        bf16x8 bf = *(const bf16x8*)(sW + (ob ^ ((c & 7) << 4)));
        a2[0][nt] = __builtin_amdgcn_mfma_f32_16x16x32_bf16(af0, bf, a2[0][nt], 0, 0, 0);
        a2[1][nt] = __builtin_amdgcn_mfma_f32_16x16x32_bf16(af1, bf, a2[1][nt], 0, 0, 0);
      }
    }
    float b2v[4], w3v[4];
#pragma unroll
    for (int nt = 0; nt < 4; ++nt) {
      int c = (nt << 4) + l15;
      b2v[nt] = b2[c];
      w3v[nt] = W3[c];
    }
    float b3v = b3[0];
#pragma unroll
    for (int mt = 0; mt < 2; ++mt)
#pragma unroll
      for (int rg = 0; rg < 4; ++rg) {
        float t = 0.f;
#pragma unroll
        for (int nt = 0; nt < 4; ++nt)
          t = fmaf(fmaxf(a2[mt][nt][rg] + b2v[nt], 0.f), w3v[nt], t);
        t += __shfl_xor(t, 1, 64);
        t += __shfl_xor(t, 2, 64);
        t += __shfl_xor(t, 4, 64);
        t += __shfl_xor(t, 8, 64);
        int r = row0 + wm + mt * 16 + lq * 4 + rg;
        if (l15 == 0 && r < M) pred[r] = t + b3v;
      }
  }
}

// ---- counting sort (fine buckets only) ------------------------------------
__global__ void hist2_k(const int* __restrict__ de, const int* __restrict__ dm,
                        int* __restrict__ cnt) {
  int e = blockIdx.x * 256 + threadIdx.x;
  if (e < NEDGE) atomicAdd(&cnt[de[e]], 1);
  else if (e < 2 * NEDGE) atomicAdd(&cnt[NM_N + dm[e - NEDGE]], 1);
}

__global__ __launch_bounds__(256) void scanA_k(const int* __restrict__ cnt,
                                               int* __restrict__ offs,
                                               int* __restrict__ sums, int n) {
  __shared__ int ts[256];
  int tid = threadIdx.x;
  int base = blockIdx.x * 4096 + tid * 16;
  int v[16];
  int s = 0;
#pragma unroll
  for (int i = 0; i < 16; ++i) {
    v[i] = (base + i < n) ? cnt[base + i] : 0;
    s += v[i];
  }
  ts[tid] = s;
  __syncthreads();
  for (int off = 1; off < 256; off <<= 1) {
    int t = (tid >= off) ? ts[tid - off] : 0;
    __syncthreads();
    ts[tid] += t;
    __syncthreads();
  }
  int run = ts[tid] - s;
#pragma unroll
  for (int i = 0; i < 16; ++i) {
    if (base + i < n) offs[base + i] = run;
    run += v[i];
  }
  if (tid == 255) sums[blockIdx.x] = ts[255];
}

__global__ void scanB_k(int* __restrict__ sums, int nchunk) {
  if (threadIdx.x == 0) {
    int acc = 0;
    for (int i = 0; i < nchunk; ++i) {
      int t = sums[i];
      sums[i] = acc;
      acc += t;
    }
    sums[nchunk] = acc;
  }
}

__global__ void scanC_k(int* __restrict__ offs, const int* __restrict__ sums, int n) {
  int i = blockIdx.x * blockDim.x + threadIdx.x;
  if (i < n) offs[i] += sums[i >> 12];
  if (i == 0) offs[n] = sums[(n + 4095) >> 12];
}

__global__ void scatter2_k(const int* __restrict__ se, const int* __restrict__ de,
                           const int* __restrict__ sm, const int* __restrict__ dm,
                           const int* __restrict__ offs, int* __restrict__ cur,
                           ushort* __restrict__ ssrc) {
  int e = blockIdx.x * 256 + threadIdx.x;
  if (e >= 2 * NEDGE) return;
  int s, db;
  if (e < NEDGE) { s = se[e]; db = de[e]; }
  else { s = sm[e - NEDGE]; db = NM_N + dm[e - NEDGE]; }
  int pos = offs[db] + atomicAdd(&cur[db], 1);
  ssrc[pos] = (ushort)s;
}

// ---- per-dst softmax aggregation (bf16 hs), unshifted exp, 8-wide ---------
__global__ __launch_bounds__(256) void gat_agg_k(const ushort* __restrict__ hs,
    const float* __restrict__ als, const float* __restrict__ ald,
    const int* __restrict__ offs, const ushort* __restrict__ ssrc,
    const float* __restrict__ bias, float* __restrict__ out,
    ushort* __restrict__ outB, int Ndst,
    const float* __restrict__ Vald, float* __restrict__ aldOut) {
  const int lane = threadIdx.x & 63;
  const int n = (blockIdx.x * 256 + threadIdx.x) >> 6;
  if (n >= Ndst) return;
  const int h = lane >> 4;
  const uint* hsu = (const uint*)hs;
  const float ad = ald[(size_t)n * 4 + h];
  const int i0 = offs[n], i1 = offs[n + 1];
  float den0 = 0.f, den1 = 0.f, acc0 = 0.f, acc1 = 0.f;
  int i = i0;
  for (; i + 8 <= i1; i += 8) {
    int s[8];
#pragma unroll
    for (int k = 0; k < 8; ++k) s[k] = (int)ssrc[i + k];
    float p[8];
#pragma unroll
    for (int k = 0; k < 8; ++k) {
      float e = als[(size_t)s[k] * 4 + h] + ad;
      e = (e > 0.f) ? e : 0.2f * e;
      p[k] = __expf(e);
    }
    uint u[8];
#pragma unroll
    for (int k = 0; k < 8; ++k) u[k] = hsu[(size_t)s[k] * 64 + lane];
#pragma unroll
    for (int k = 0; k < 8; ++k) {
      acc0 = fmaf(p[k], bfl(u[k]), acc0);
      acc1 = fmaf(p[k], bfh(u[k]), acc1);
      if (k & 1) den1 += p[k]; else den0 += p[k];
    }
  }
  for (; i < i1; ++i) {
    int s0 = (int)ssrc[i];
    float e = als[(size_t)s0 * 4 + h] + ad;
    e = (e > 0.f) ? e : 0.2f * e;
    float p0 = __expf(e);
    uint u0 = hsu[(size_t)s0 * 64 + lane];
    acc0 = fmaf(p0, bfl(u0), acc0);
    acc1 = fmaf(p0, bfh(u0), acc1);
    den0 += p0;
  }
  const float inv = 1.f / (den0 + den1 + 1e-16f);
  float r0 = acc0 * inv + bias[2 * lane];
  float r1 = acc1 * inv + bias[2 * lane + 1];
  r0 = (r0 > 0.f) ? r0 : expm1f(r0);  // ELU
  r1 = (r1 > 0.f) ? r1 : expm1f(r1);
  if (out)
    *(float2*)&out[(size_t)n * 128 + 2 * lane] = make_float2(r0, r1);
  if (outB)
    ((uint*)outB)[(size_t)n * 64 + lane] = (uint)f2bf(r0) | ((uint)f2bf(r1) << 16);
  if (Vald) {
    const float4 w0 = *(const float4*)&Vald[(2 * lane) * 4];
    const float4 w1 = *(const float4*)&Vald[(2 * lane + 1) * 4];
    float t0 = fmaf(r0, w0.x, r1 * w1.x);
    float t1 = fmaf(r0, w0.y, r1 * w1.y);
    float t2 = fmaf(r0, w0.z, r1 * w1.z);
    float t3 = fmaf(r0, w0.w, r1 * w1.w);
#pragma unroll
    for (int off = 1; off < 64; off <<= 1) {
      t0 += __shfl_xor(t0, off, 64);
      t1 += __shfl_xor(t1, off, 64);
      t2 += __shfl_xor(t2, off, 64);
      t3 += __shfl_xor(t3, off, 64);
    }
    if (lane == 0)
      *(float4*)&aldOut[(size_t)n * 4] = make_float4(t0, t1, t2, t3);
  }
}

extern "C" void kernel_launch(void* const* d_in, const int* in_sizes, int n_in,
                              void* d_out, int out_size, void* d_ws, size_t ws_size,
                              hipStream_t stream) {
  const float* x_exp   = (const float*)d_in[0];
  const float* x_mat   = (const float*)d_in[1];
  const int*   ei_em   = (const int*)d_in[2];
  const int*   ei_me   = (const int*)d_in[3];
  const float* Win_exp = (const float*)d_in[4];
  const float* bin_exp = (const float*)d_in[5];
  const float* Win_mat = (const float*)d_in[6];
  const float* bin_mat = (const float*)d_in[7];
  const float* Wsrc_em = (const float*)d_in[8];
  const float* Wdst_em = (const float*)d_in[9];
  const float* asrc_em = (const float*)d_in[10];
  const float* adst_em = (const float*)d_in[11];
  const float* b_em    = (const float*)d_in[12];
  const float* Wsrc_me = (const float*)d_in[13];
  const float* Wdst_me = (const float*)d_in[14];
  const float* asrc_me = (const float*)d_in[15];
  const float* adst_me = (const float*)d_in[16];
  const float* b_me    = (const float*)d_in[17];
  const float* Wr1     = (const float*)d_in[18];
  const float* br1     = (const float*)d_in[19];
  const float* Wr2     = (const float*)d_in[20];
  const float* br2     = (const float*)d_in[21];
  const float* Wr3     = (const float*)d_in[22];
  const float* br3     = (const float*)d_in[23];

  float* pred = (float*)d_out;
  float* heO  = pred + NE_N;
  float* hmO  = heO + (size_t)NE_N * 128;

  ushort* bufA  = (ushort*)d_ws;                  // 4 x 12.8MB bf16 buffers
  ushort* bufB  = bufA + (size_t)6400000;
  ushort* bufC  = bufB + (size_t)6400000;
  ushort* bufD  = bufC + (size_t)6400000;
  ushort* Wt    = bufD + (size_t)6400000;         // 5 x 16384 bf16
  ushort* VcTa  = Wt + 5 * 16384;                 // 16x128 bf16
  ushort* VcTb  = VcTa + 2048;
  float*  bc    = (float*)(VcTb + 2048);          // 2 x 128 composite biases
  float*  bias4 = bc + 256;                       // 2 x 4
  float*  alsE  = bias4 + 8;
  float*  alsM  = alsE + 200000;
  float*  aldE  = alsM + 200000;
  float*  aldM  = aldE + 200000;
  float*  Vb    = aldM + 200000;                  // 4 x 512 fp32 v0 folds
  int*    sums  = (int*)(Vb + 2048);              // 32
  int*    cnt   = sums + 32;                      // 100k (also fine cur)
  int*    offs  = cnt + 100000;                   // 100001
  ushort* ssrc  = (ushort*)(offs + 100001);       // 1M ushort (2MB)

  const int* se = ei_em;
  const int* de = ei_em + NEDGE;
  const int* sm = ei_me;
  const int* dm = ei_me + NEDGE;

  const int gE2 = (2 * NEDGE + 255) / 256;
  const int gWave = (NE_N + 3) / 4;
  const int gGemm = (NE_N + 127) / 128;
  const int nChunk = (100000 + 4095) / 4096;

  // ---- counting sort (both edge types, 100k fine buckets) ----
  hipMemsetAsync(cnt, 0, 100000 * sizeof(int), stream);
  hist2_k<<<gE2, 256, 0, stream>>>(de, dm, cnt);
  scanA_k<<<nChunk, 256, 0, stream>>>(cnt, offs, sums, 100000);
  scanB_k<<<1, 64, 0, stream>>>(sums, nChunk);
  scanC_k<<<(100000 + 255) / 256, 256, 0, stream>>>(offs, sums, 100000);
  hipMemsetAsync(cnt, 0, 100000 * sizeof(int), stream);
  scatter2_k<<<gE2, 256, 0, stream>>>(se, de, sm, dm, offs, cnt, ssrc);

  // ---- weight prep ----
  cmm_k<<<2, 256, 0, stream>>>(Win_exp, bin_exp, Wsrc_em, Win_mat, bin_mat,
                               Wsrc_me, Wt, bc);
  wcast3_k<<<3, 256, 0, stream>>>(Wsrc_em + 16384, Wsrc_me + 16384, Wr1, Wt);
  vfold4_k<<<4, 512, 0, stream>>>(Wdst_em, adst_em, Wdst_me, adst_me, Vb);
  smallprep_k<<<2, 512, 0, stream>>>(Win_exp, bin_exp, Win_mat, bin_mat, Vb,
                                     VcTa, VcTb, bias4);

  const int* offs_em = offs;
  const int* offs_me = offs + NM_N;

  // ---- layer 1 composite GEMMs: x -> hs (+als, +composite ald4) ----
  mgemm_k<<<gGemm, 256, 0, stream>>>(nullptr, x_exp, Wt, bc, bufC, NE_N, 0,
                                     asrc_em, alsE, VcTa, bias4, aldE,
                                     nullptr, nullptr, nullptr, nullptr, nullptr);
  mgemm_k<<<gGemm, 256, 0, stream>>>(nullptr, x_mat, Wt + 16384, bc + 128, bufD,
                                     NM_N, 0, asrc_me, alsM, VcTb, bias4 + 4, aldM,
                                     nullptr, nullptr, nullptr, nullptr, nullptr);

  // ---- layer 1 aggregations ----
  gat_agg_k<<<gWave, 256, 0, stream>>>(bufC, alsE, aldM, offs_em, ssrc, b_em,
                                       nullptr, bufA, NM_N, Vb + 1024, aldM);  // hm1
  gat_agg_k<<<gWave, 256, 0, stream>>>(bufD, alsM, aldE, offs_me, ssrc, b_me,
                                       nullptr, bufB, NE_N, Vb + 1536, aldE);  // he1

  // ---- layer 2 GEMMs ----
  mgemm_k<<<gGemm, 256, 0, stream>>>(bufB, nullptr, Wt + 2 * 16384, nullptr, bufC,
                                     NE_N, 0, asrc_em + 128, alsE,
                                     nullptr, nullptr, nullptr,
                                     nullptr, nullptr, nullptr, nullptr, nullptr);
  mgemm_k<<<gGemm, 256, 0, stream>>>(bufA, nullptr, Wt + 3 * 16384, nullptr, bufD,
                                     NM_N, 0, asrc_me + 128, alsM,
                                     nullptr, nullptr, nullptr,
                                     nullptr, nullptr, nullptr, nullptr, nullptr);

  // ---- layer 2 aggregations ----
  gat_agg_k<<<gWave, 256, 0, stream>>>(bufC, alsE, aldM, offs_em, ssrc,
                                       b_em + 128, hmO, nullptr, NM_N,
                                       nullptr, nullptr);
  gat_agg_k<<<gWave, 256, 0, stream>>>(bufD, alsM, aldE, offs_me, ssrc,
                                       b_me + 128, heO, bufA, NE_N,
                                       nullptr, nullptr);

  // ---- regressor: fused h1-GEMM + MLP tail -> pred ----
  mgemm_k<<<gGemm, 256, 0, stream>>>(bufA, nullptr, Wt + 4 * 16384, br1, nullptr,
                                     NE_N, 1, nullptr, nullptr,
                                     nullptr, nullptr, nullptr,
                                     Wr2, br2, Wr3, br3, pred);
}